// Round 2
// baseline (616.994 us; speedup 1.0000x reference)
//
#include <hip/hip_runtime.h>
#include <cstdint>
#include <cstddef>

constexpr int D = 64;
constexpr int TWO_D = 128;

// ---------------------------------------------------------------------------
// Kernel 1: projection tables as a tiled fp32 GEMM.
//   blocks [0, nPB):        P[r,:] = v_to_e[r,:]        . att1_w[:, 0:D]^T
//   blocks [nPB, nPB+nSB):  S[b,:] = u_to_e[nodes[b],:] . att1_w[:, D:2D]^T + b1
// Tile: 128 rows x 64 outputs, 128 threads (2 waves), 8r x 8d per thread.
// X tile and W1 half staged TRANSPOSED in padded LDS so all compute reads are
// 16B-aligned ds_read_b128 with near-zero bank conflicts.
// ---------------------------------------------------------------------------
__global__ __launch_bounds__(128) void proj_gemm(
    const float* __restrict__ v_to_e, const float* __restrict__ u_to_e,
    const int* __restrict__ nodes,
    const float* __restrict__ att1_w, const float* __restrict__ att1_b,
    float* __restrict__ P, float* __restrict__ S, int NV, int Bn, int nPB)
{
    constexpr int XS = 132;   // padded row stride for xs[f][r]  (128 + 4)
    constexpr int WS = 68;    // padded row stride for ws[f][d]  (64 + 4)
    __shared__ float xs[64 * XS];   // 33792 f  (~33 KB)
    __shared__ float ws[64 * WS];   // 17408 f  (~17 KB)   total 50 KB -> 3 blk/CU

    const int tid  = threadIdx.x;
    const bool isS = ((int)blockIdx.x >= nPB);
    const int base = (isS ? ((int)blockIdx.x - nPB) : (int)blockIdx.x) * 128;
    const int nRows = isS ? Bn : NV;
    const int woff  = isS ? D : 0;
    const float* X  = isS ? u_to_e : v_to_e;
    float* Out      = isS ? S : P;

    // ---- stage W1 half transposed: ws[f][d]. 64 d x 16 f4 chunks = 1024 float4.
#pragma unroll
    for (int it = 0; it < 8; ++it) {
        const int flat = it * 128 + tid;
        const int dd = flat >> 4, f4 = flat & 15;
        const float4 w = *(const float4*)(att1_w + dd * TWO_D + woff + f4 * 4);
        ws[(f4 * 4 + 0) * WS + dd] = w.x;
        ws[(f4 * 4 + 1) * WS + dd] = w.y;
        ws[(f4 * 4 + 2) * WS + dd] = w.z;
        ws[(f4 * 4 + 3) * WS + dd] = w.w;
    }
    // ---- stage X tile transposed: xs[f][r]. 128 rows x 16 f4 = 2048 float4.
#pragma unroll
    for (int it = 0; it < 16; ++it) {
        const int flat = it * 128 + tid;
        const int r = flat >> 4, f4 = flat & 15;
        int gr = base + r;
        if (gr >= nRows) gr = nRows - 1;           // clamp for tail tile
        const int row = isS ? nodes[gr] : gr;
        const float4 x = *(const float4*)(X + (size_t)row * D + f4 * 4);
        xs[(f4 * 4 + 0) * XS + r] = x.x;
        xs[(f4 * 4 + 1) * XS + r] = x.y;
        xs[(f4 * 4 + 2) * XS + r] = x.z;
        xs[(f4 * 4 + 3) * XS + r] = x.w;
    }
    __syncthreads();

    // ---- compute: 8 d-groups x 16 r-groups; thread owns 8r x 8d.
    const int d0 = (tid & 7) * 8;
    const int r0 = (tid >> 3) * 8;
    float acc[8][8];
#pragma unroll
    for (int i = 0; i < 8; ++i)
#pragma unroll
        for (int j = 0; j < 8; ++j) acc[i][j] = 0.f;

#pragma unroll
    for (int f = 0; f < D; ++f) {
        const float4 w0 = *(const float4*)&ws[f * WS + d0];
        const float4 w1 = *(const float4*)&ws[f * WS + d0 + 4];
        const float4 x0 = *(const float4*)&xs[f * XS + r0];
        const float4 x1 = *(const float4*)&xs[f * XS + r0 + 4];
        const float wv[8] = {w0.x, w0.y, w0.z, w0.w, w1.x, w1.y, w1.z, w1.w};
        const float xv[8] = {x0.x, x0.y, x0.z, x0.w, x1.x, x1.y, x1.z, x1.w};
#pragma unroll
        for (int ri = 0; ri < 8; ++ri)
#pragma unroll
            for (int di = 0; di < 8; ++di)
                acc[ri][di] += xv[ri] * wv[di];
    }

    float bv[8];
#pragma unroll
    for (int di = 0; di < 8; ++di) bv[di] = isS ? att1_b[d0 + di] : 0.f;

#pragma unroll
    for (int ri = 0; ri < 8; ++ri) {
        const int gr = base + r0 + ri;
        if (gr < nRows) {
            float4 o0 = {acc[ri][0] + bv[0], acc[ri][1] + bv[1],
                         acc[ri][2] + bv[2], acc[ri][3] + bv[3]};
            float4 o1 = {acc[ri][4] + bv[4], acc[ri][5] + bv[5],
                         acc[ri][6] + bv[6], acc[ri][7] + bv[7]};
            *(float4*)(Out + (size_t)gr * D + d0)     = o0;
            *(float4*)(Out + (size_t)gr * D + d0 + 4) = o1;
        }
    }
}

// ---------------------------------------------------------------------------
// Kernel 2: one wave per node b. Lane k owns neighbor k. (unchanged from R1
// except unroll 4 on the e-loop) — this is next round's profiling target.
// ---------------------------------------------------------------------------
template <bool HAS_WS>
__global__ __launch_bounds__(256) void agg_kernel(
    const int* __restrict__ nodes, const int* __restrict__ history,
    const int* __restrict__ degrees,
    const float* __restrict__ u_to_e, const float* __restrict__ v_to_e,
    const float* __restrict__ att1_w, const float* __restrict__ att1_b,
    const float* __restrict__ att2_w, const float* __restrict__ att2_b,
    const float* __restrict__ att3_w, const float* __restrict__ att3_b,
    const float* __restrict__ P, const float* __restrict__ S,
    float* __restrict__ out, int Bn, int K)
{
    const int b    = (int)((blockIdx.x * blockDim.x + threadIdx.x) >> 6);
    const int lane = threadIdx.x & 63;
    if (b >= Bn) return;

    const int  deg    = degrees[b];            // wave-uniform
    const bool active = (lane < deg);
    const int  v      = history[(size_t)b * K + ((lane < K) ? lane : 0)];

    // ---- phase A: h1 = relu(P[v] + S[b]) ----
    float h1[D];
    if (HAS_WS) {
        const float4* p4 = (const float4*)(P + (size_t)v * D);
        const float4* s4 = (const float4*)(S + (size_t)b * D);  // uniform
#pragma unroll
        for (int i = 0; i < D / 4; ++i) {
            float4 p = p4[i];
            float4 s = s4[i];
            h1[4 * i + 0] = fmaxf(p.x + s.x, 0.f);
            h1[4 * i + 1] = fmaxf(p.y + s.y, 0.f);
            h1[4 * i + 2] = fmaxf(p.z + s.z, 0.f);
            h1[4 * i + 3] = fmaxf(p.w + s.w, 0.f);
        }
    } else {
        float vr[D];
        const float4* v4 = (const float4*)(v_to_e + (size_t)v * D);
#pragma unroll
        for (int i = 0; i < D / 4; ++i) {
            float4 t = v4[i];
            vr[4 * i + 0] = t.x; vr[4 * i + 1] = t.y;
            vr[4 * i + 2] = t.z; vr[4 * i + 3] = t.w;
        }
        const float* urow = u_to_e + (size_t)nodes[b] * D;  // uniform
#pragma unroll
        for (int d = 0; d < D; ++d) {
            const float* w1 = att1_w + d * TWO_D;
            float a0 = att1_b[d], a1 = 0.f, a2 = 0.f, a3 = 0.f;
#pragma unroll
            for (int f = 0; f < D; f += 4) {
                a0 += vr[f + 0] * w1[f + 0];
                a1 += vr[f + 1] * w1[f + 1];
                a2 += vr[f + 2] * w1[f + 2];
                a3 += vr[f + 3] * w1[f + 3];
                a0 += urow[f + 0] * w1[D + f + 0];
                a1 += urow[f + 1] * w1[D + f + 1];
                a2 += urow[f + 2] * w1[D + f + 2];
                a3 += urow[f + 3] * w1[D + f + 3];
            }
            h1[d] = fmaxf((a0 + a1) + (a2 + a3), 0.f);
        }
    }

    // ---- phase B: logit = b3 + w3 . relu(W2 . h1 + b2) ----
    float logit = att3_b[0];
#pragma unroll 4
    for (int e = 0; e < D; ++e) {
        const float* w2r = att2_w + e * D;   // loop-uniform row -> s_load
        float a0 = 0.f, a1 = 0.f, a2 = 0.f, a3 = 0.f;
#pragma unroll
        for (int dd = 0; dd < D; dd += 4) {
            a0 += h1[dd + 0] * w2r[dd + 0];
            a1 += h1[dd + 1] * w2r[dd + 1];
            a2 += h1[dd + 2] * w2r[dd + 2];
            a3 += h1[dd + 3] * w2r[dd + 3];
        }
        float h2 = (a0 + a1) + (a2 + a3) + att2_b[e];
        h2 = fmaxf(h2, 0.f);
        logit += h2 * att3_w[e];
    }

    // ---- phase C: masked softmax across lanes (ragged neighbor set) ----
    float ml = active ? logit : -1e30f;
#pragma unroll
    for (int off = 32; off > 0; off >>= 1)
        ml = fmaxf(ml, __shfl_xor(ml, off));
    const float ex = active ? __expf(logit - ml) : 0.f;
    float sm = ex;
#pragma unroll
    for (int off = 32; off > 0; off >>= 1)
        sm += __shfl_xor(sm, off);
    const float att = ex / sm;

    // ---- phase D: out[b, lane] = sum_k att_k * v_to_e[v_k, lane] ----
    float acc = 0.f;
    for (int kk = 0; kk < deg; ++kk) {
        const float a  = __shfl(att, kk);
        const int   vk = __shfl(v, kk);
        acc += a * v_to_e[(size_t)vk * D + lane];
    }
    out[(size_t)b * D + lane] = acc;
}

// ---------------------------------------------------------------------------
extern "C" void kernel_launch(void* const* d_in, const int* in_sizes, int n_in,
                              void* d_out, int out_size, void* d_ws, size_t ws_size,
                              hipStream_t stream)
{
    const int*   nodes   = (const int*)d_in[0];
    const int*   history = (const int*)d_in[1];
    const int*   degrees = (const int*)d_in[2];
    const float* u_to_e  = (const float*)d_in[3];
    const float* v_to_e  = (const float*)d_in[4];
    const float* att1_w  = (const float*)d_in[5];
    const float* att1_b  = (const float*)d_in[6];
    const float* att2_w  = (const float*)d_in[7];
    const float* att2_b  = (const float*)d_in[8];
    const float* att3_w  = (const float*)d_in[9];
    const float* att3_b  = (const float*)d_in[10];
    float*       out     = (float*)d_out;

    const int Bn = in_sizes[0];
    const int K  = in_sizes[1] / Bn;
    const int NV = in_sizes[4] / D;

    const size_t need = ((size_t)NV + (size_t)Bn) * D * sizeof(float);
    const int agg_blocks = (Bn * 64 + 255) / 256;

    if (ws_size >= need) {
        float* P = (float*)d_ws;
        float* S = P + (size_t)NV * D;
        const int nPB = (NV + 127) / 128;
        const int nSB = (Bn + 127) / 128;
        proj_gemm<<<nPB + nSB, 128, 0, stream>>>(
            v_to_e, u_to_e, nodes, att1_w, att1_b, P, S, NV, Bn, nPB);
        agg_kernel<true><<<agg_blocks, 256, 0, stream>>>(
            nodes, history, degrees, u_to_e, v_to_e,
            att1_w, att1_b, att2_w, att2_b, att3_w, att3_b,
            P, S, out, Bn, K);
    } else {
        agg_kernel<false><<<agg_blocks, 256, 0, stream>>>(
            nodes, history, degrees, u_to_e, v_to_e,
            att1_w, att1_b, att2_w, att2_b, att3_w, att3_b,
            nullptr, nullptr, out, Bn, K);
    }
}

// Round 3
// 122.410 us; speedup vs baseline: 5.0404x; 5.0404x over previous
//
#include <hip/hip_runtime.h>
#include <cstdint>
#include <cstddef>

constexpr int D = 64;
constexpr int TWO_D = 128;

// ---------------------------------------------------------------------------
// Kernel 1: projection tables as a tiled fp32 GEMM (spill-safe sizing).
//   blocks [0, nPB):        P[r,:] = v_to_e[r,:]        . att1_w[:, 0:D]^T
//   blocks [nPB, nPB+nSB):  S[b,:] = u_to_e[nodes[b],:] . att1_w[:, D:2D]^T + b1
// Tile: 64 rows x 64 outputs, 256 threads, 4r x 4d per thread (16 acc VGPRs).
// X tile and W1 half staged TRANSPOSED in padded LDS (stride 68 keeps 16B
// alignment); compute reads are conflict-free ds_read_b128.
// ---------------------------------------------------------------------------
__global__ __launch_bounds__(256) void proj_gemm(
    const float* __restrict__ v_to_e, const float* __restrict__ u_to_e,
    const int* __restrict__ nodes,
    const float* __restrict__ att1_w, const float* __restrict__ att1_b,
    float* __restrict__ P, float* __restrict__ S, int NV, int Bn, int nPB)
{
    constexpr int ST = 68;           // 68*4 = 272 B stride, 16B-aligned
    __shared__ float xs[64 * ST];    // 17.4 KB
    __shared__ float ws[64 * ST];    // 17.4 KB  (total ~35 KB -> 4 blk/CU)

    const int tid  = threadIdx.x;
    const bool isS = ((int)blockIdx.x >= nPB);
    const int base = (isS ? ((int)blockIdx.x - nPB) : (int)blockIdx.x) * 64;
    const int nRows = isS ? Bn : NV;
    const int woff  = isS ? D : 0;
    const float* X  = isS ? u_to_e : v_to_e;
    float* Out      = isS ? S : P;

    // ---- stage W1 half transposed: ws[f][d]. 64x64 floats = 1024 float4.
#pragma unroll
    for (int it = 0; it < 4; ++it) {
        const int flat = it * 256 + tid;
        const int dd = flat >> 4, f4 = flat & 15;
        const float4 w = *(const float4*)(att1_w + dd * TWO_D + woff + f4 * 4);
        ws[(f4 * 4 + 0) * ST + dd] = w.x;
        ws[(f4 * 4 + 1) * ST + dd] = w.y;
        ws[(f4 * 4 + 2) * ST + dd] = w.z;
        ws[(f4 * 4 + 3) * ST + dd] = w.w;
    }
    // ---- stage X tile transposed: xs[f][r]. 64 rows x 16 f4 = 1024 float4.
#pragma unroll
    for (int it = 0; it < 4; ++it) {
        const int flat = it * 256 + tid;
        const int r = flat >> 4, f4 = flat & 15;
        int gr = base + r;
        if (gr >= nRows) gr = nRows - 1;           // clamp for tail tile
        const int row = isS ? nodes[gr] : gr;
        const float4 x = *(const float4*)(X + (size_t)row * D + f4 * 4);
        xs[(f4 * 4 + 0) * ST + r] = x.x;
        xs[(f4 * 4 + 1) * ST + r] = x.y;
        xs[(f4 * 4 + 2) * ST + r] = x.z;
        xs[(f4 * 4 + 3) * ST + r] = x.w;
    }
    __syncthreads();

    // ---- compute: thread owns 4r x 4d. 16 accumulators, unroll 8.
    const int d0 = (tid & 15) * 4;
    const int r0 = (tid >> 4) * 4;
    float acc[4][4];
#pragma unroll
    for (int i = 0; i < 4; ++i)
#pragma unroll
        for (int j = 0; j < 4; ++j) acc[i][j] = 0.f;

#pragma unroll 8
    for (int f = 0; f < D; ++f) {
        const float4 w = *(const float4*)&ws[f * ST + d0];
        const float4 x = *(const float4*)&xs[f * ST + r0];
        const float wv[4] = {w.x, w.y, w.z, w.w};
        const float xv[4] = {x.x, x.y, x.z, x.w};
#pragma unroll
        for (int ri = 0; ri < 4; ++ri)
#pragma unroll
            for (int di = 0; di < 4; ++di)
                acc[ri][di] += xv[ri] * wv[di];
    }

    float bv[4];
#pragma unroll
    for (int di = 0; di < 4; ++di) bv[di] = isS ? att1_b[d0 + di] : 0.f;

#pragma unroll
    for (int ri = 0; ri < 4; ++ri) {
        const int gr = base + r0 + ri;
        if (gr < nRows) {
            float4 o = {acc[ri][0] + bv[0], acc[ri][1] + bv[1],
                        acc[ri][2] + bv[2], acc[ri][3] + bv[3]};
            *(float4*)(Out + (size_t)gr * D + d0) = o;
        }
    }
}

// ---------------------------------------------------------------------------
// Kernel 2: one wave per node b. Lane k owns neighbor k. (unchanged —
// next round's profiling target.)
// ---------------------------------------------------------------------------
template <bool HAS_WS>
__global__ __launch_bounds__(256) void agg_kernel(
    const int* __restrict__ nodes, const int* __restrict__ history,
    const int* __restrict__ degrees,
    const float* __restrict__ u_to_e, const float* __restrict__ v_to_e,
    const float* __restrict__ att1_w, const float* __restrict__ att1_b,
    const float* __restrict__ att2_w, const float* __restrict__ att2_b,
    const float* __restrict__ att3_w, const float* __restrict__ att3_b,
    const float* __restrict__ P, const float* __restrict__ S,
    float* __restrict__ out, int Bn, int K)
{
    const int b    = (int)((blockIdx.x * blockDim.x + threadIdx.x) >> 6);
    const int lane = threadIdx.x & 63;
    if (b >= Bn) return;

    const int  deg    = degrees[b];            // wave-uniform
    const bool active = (lane < deg);
    const int  v      = history[(size_t)b * K + ((lane < K) ? lane : 0)];

    // ---- phase A: h1 = relu(P[v] + S[b]) ----
    float h1[D];
    if (HAS_WS) {
        const float4* p4 = (const float4*)(P + (size_t)v * D);
        const float4* s4 = (const float4*)(S + (size_t)b * D);  // uniform
#pragma unroll
        for (int i = 0; i < D / 4; ++i) {
            float4 p = p4[i];
            float4 s = s4[i];
            h1[4 * i + 0] = fmaxf(p.x + s.x, 0.f);
            h1[4 * i + 1] = fmaxf(p.y + s.y, 0.f);
            h1[4 * i + 2] = fmaxf(p.z + s.z, 0.f);
            h1[4 * i + 3] = fmaxf(p.w + s.w, 0.f);
        }
    } else {
        float vr[D];
        const float4* v4 = (const float4*)(v_to_e + (size_t)v * D);
#pragma unroll
        for (int i = 0; i < D / 4; ++i) {
            float4 t = v4[i];
            vr[4 * i + 0] = t.x; vr[4 * i + 1] = t.y;
            vr[4 * i + 2] = t.z; vr[4 * i + 3] = t.w;
        }
        const float* urow = u_to_e + (size_t)nodes[b] * D;  // uniform
#pragma unroll
        for (int d = 0; d < D; ++d) {
            const float* w1 = att1_w + d * TWO_D;
            float a0 = att1_b[d], a1 = 0.f, a2 = 0.f, a3 = 0.f;
#pragma unroll
            for (int f = 0; f < D; f += 4) {
                a0 += vr[f + 0] * w1[f + 0];
                a1 += vr[f + 1] * w1[f + 1];
                a2 += vr[f + 2] * w1[f + 2];
                a3 += vr[f + 3] * w1[f + 3];
                a0 += urow[f + 0] * w1[D + f + 0];
                a1 += urow[f + 1] * w1[D + f + 1];
                a2 += urow[f + 2] * w1[D + f + 2];
                a3 += urow[f + 3] * w1[D + f + 3];
            }
            h1[d] = fmaxf((a0 + a1) + (a2 + a3), 0.f);
        }
    }

    // ---- phase B: logit = b3 + w3 . relu(W2 . h1 + b2) ----
    float logit = att3_b[0];
#pragma unroll 4
    for (int e = 0; e < D; ++e) {
        const float* w2r = att2_w + e * D;   // loop-uniform row -> s_load
        float a0 = 0.f, a1 = 0.f, a2 = 0.f, a3 = 0.f;
#pragma unroll
        for (int dd = 0; dd < D; dd += 4) {
            a0 += h1[dd + 0] * w2r[dd + 0];
            a1 += h1[dd + 1] * w2r[dd + 1];
            a2 += h1[dd + 2] * w2r[dd + 2];
            a3 += h1[dd + 3] * w2r[dd + 3];
        }
        float h2 = (a0 + a1) + (a2 + a3) + att2_b[e];
        h2 = fmaxf(h2, 0.f);
        logit += h2 * att3_w[e];
    }

    // ---- phase C: masked softmax across lanes (ragged neighbor set) ----
    float ml = active ? logit : -1e30f;
#pragma unroll
    for (int off = 32; off > 0; off >>= 1)
        ml = fmaxf(ml, __shfl_xor(ml, off));
    const float ex = active ? __expf(logit - ml) : 0.f;
    float sm = ex;
#pragma unroll
    for (int off = 32; off > 0; off >>= 1)
        sm += __shfl_xor(sm, off);
    const float att = ex / sm;

    // ---- phase D: out[b, lane] = sum_k att_k * v_to_e[v_k, lane] ----
    float acc = 0.f;
    for (int kk = 0; kk < deg; ++kk) {
        const float a  = __shfl(att, kk);
        const int   vk = __shfl(v, kk);
        acc += a * v_to_e[(size_t)vk * D + lane];
    }
    out[(size_t)b * D + lane] = acc;
}

// ---------------------------------------------------------------------------
extern "C" void kernel_launch(void* const* d_in, const int* in_sizes, int n_in,
                              void* d_out, int out_size, void* d_ws, size_t ws_size,
                              hipStream_t stream)
{
    const int*   nodes   = (const int*)d_in[0];
    const int*   history = (const int*)d_in[1];
    const int*   degrees = (const int*)d_in[2];
    const float* u_to_e  = (const float*)d_in[3];
    const float* v_to_e  = (const float*)d_in[4];
    const float* att1_w  = (const float*)d_in[5];
    const float* att1_b  = (const float*)d_in[6];
    const float* att2_w  = (const float*)d_in[7];
    const float* att2_b  = (const float*)d_in[8];
    const float* att3_w  = (const float*)d_in[9];
    const float* att3_b  = (const float*)d_in[10];
    float*       out     = (float*)d_out;

    const int Bn = in_sizes[0];
    const int K  = in_sizes[1] / Bn;
    const int NV = in_sizes[4] / D;

    const size_t need = ((size_t)NV + (size_t)Bn) * D * sizeof(float);
    const int agg_blocks = (Bn * 64 + 255) / 256;

    if (ws_size >= need) {
        float* P = (float*)d_ws;
        float* S = P + (size_t)NV * D;
        const int nPB = (NV + 63) / 64;
        const int nSB = (Bn + 63) / 64;
        proj_gemm<<<nPB + nSB, 256, 0, stream>>>(
            v_to_e, u_to_e, nodes, att1_w, att1_b, P, S, NV, Bn, nPB);
        agg_kernel<true><<<agg_blocks, 256, 0, stream>>>(
            nodes, history, degrees, u_to_e, v_to_e,
            att1_w, att1_b, att2_w, att2_b, att3_w, att3_b,
            P, S, out, Bn, K);
    } else {
        agg_kernel<false><<<agg_blocks, 256, 0, stream>>>(
            nodes, history, degrees, u_to_e, v_to_e,
            att1_w, att1_b, att2_w, att2_b, att3_w, att3_b,
            nullptr, nullptr, out, Bn, K);
    }
}

// Round 4
// 83.410 us; speedup vs baseline: 7.3971x; 1.4676x over previous
//
#include <hip/hip_runtime.h>
#include <cstdint>
#include <cstddef>

constexpr int D = 64;
constexpr int TWO_D = 128;

typedef __attribute__((ext_vector_type(8))) short bf16x8;
typedef __attribute__((ext_vector_type(4))) float f32x4;

static __device__ __forceinline__ short f2bf(float x) {
    unsigned u = __builtin_bit_cast(unsigned, x);
    u += 0x7fffu + ((u >> 16) & 1u);          // round-to-nearest-even
    return (short)(u >> 16);
}

// ---------------------------------------------------------------------------
// Kernel 1: projection tables as a tiled fp32 GEMM (unchanged from R3).
//   blocks [0, nPB):        P[r,:] = v_to_e[r,:]        . att1_w[:, 0:D]^T
//   blocks [nPB, nPB+nSB):  S[b,:] = u_to_e[nodes[b],:] . att1_w[:, D:2D]^T + b1
// ---------------------------------------------------------------------------
__global__ __launch_bounds__(256) void proj_gemm(
    const float* __restrict__ v_to_e, const float* __restrict__ u_to_e,
    const int* __restrict__ nodes,
    const float* __restrict__ att1_w, const float* __restrict__ att1_b,
    float* __restrict__ P, float* __restrict__ S, int NV, int Bn, int nPB)
{
    constexpr int ST = 68;
    __shared__ float xs[64 * ST];
    __shared__ float ws[64 * ST];

    const int tid  = threadIdx.x;
    const bool isS = ((int)blockIdx.x >= nPB);
    const int base = (isS ? ((int)blockIdx.x - nPB) : (int)blockIdx.x) * 64;
    const int nRows = isS ? Bn : NV;
    const int woff  = isS ? D : 0;
    const float* X  = isS ? u_to_e : v_to_e;
    float* Out      = isS ? S : P;

#pragma unroll
    for (int it = 0; it < 4; ++it) {
        const int flat = it * 256 + tid;
        const int dd = flat >> 4, f4 = flat & 15;
        const float4 w = *(const float4*)(att1_w + dd * TWO_D + woff + f4 * 4);
        ws[(f4 * 4 + 0) * ST + dd] = w.x;
        ws[(f4 * 4 + 1) * ST + dd] = w.y;
        ws[(f4 * 4 + 2) * ST + dd] = w.z;
        ws[(f4 * 4 + 3) * ST + dd] = w.w;
    }
#pragma unroll
    for (int it = 0; it < 4; ++it) {
        const int flat = it * 256 + tid;
        const int r = flat >> 4, f4 = flat & 15;
        int gr = base + r;
        if (gr >= nRows) gr = nRows - 1;
        const int row = isS ? nodes[gr] : gr;
        const float4 x = *(const float4*)(X + (size_t)row * D + f4 * 4);
        xs[(f4 * 4 + 0) * ST + r] = x.x;
        xs[(f4 * 4 + 1) * ST + r] = x.y;
        xs[(f4 * 4 + 2) * ST + r] = x.z;
        xs[(f4 * 4 + 3) * ST + r] = x.w;
    }
    __syncthreads();

    const int d0 = (tid & 15) * 4;
    const int r0 = (tid >> 4) * 4;
    float acc[4][4];
#pragma unroll
    for (int i = 0; i < 4; ++i)
#pragma unroll
        for (int j = 0; j < 4; ++j) acc[i][j] = 0.f;

#pragma unroll 8
    for (int f = 0; f < D; ++f) {
        const float4 w = *(const float4*)&ws[f * ST + d0];
        const float4 x = *(const float4*)&xs[f * ST + r0];
        const float wv[4] = {w.x, w.y, w.z, w.w};
        const float xv[4] = {x.x, x.y, x.z, x.w};
#pragma unroll
        for (int ri = 0; ri < 4; ++ri)
#pragma unroll
            for (int di = 0; di < 4; ++di)
                acc[ri][di] += xv[ri] * wv[di];
    }

    float bv[4];
#pragma unroll
    for (int di = 0; di < 4; ++di) bv[di] = isS ? att1_b[d0 + di] : 0.f;

#pragma unroll
    for (int ri = 0; ri < 4; ++ri) {
        const int gr = base + r0 + ri;
        if (gr < nRows) {
            float4 o = {acc[ri][0] + bv[0], acc[ri][1] + bv[1],
                        acc[ri][2] + bv[2], acc[ri][3] + bv[3]};
            *(float4*)(Out + (size_t)gr * D + d0) = o;
        }
    }
}

// ---------------------------------------------------------------------------
// Kernel 2 (MFMA): one wave per node b (4 waves / 256-thr block).
// Score path in bf16 MFMA (fp32 accum): H2[64k x 64e] = relu(P[v]+S[b]) @ W2^T
// as 32x mfma_f32_16x16x32_bf16. Epilogue relu+b2, dot w3, shfl-reduce ->
// logits; masked softmax; att via per-wave LDS; value path stays fp32.
//
// Layouts (guide §3, m89-verified):
//   A-frag: lane l holds A[row = l&15][k = (l>>4)*8 + j], j=0..7
//   B-frag: lane l holds B[k = (l>>4)*8 + j][col = l&15]
//   C/D:    reg r of lane l = D[row = (l>>4)*4 + r][col = l&15]
// ---------------------------------------------------------------------------
__global__ __launch_bounds__(256) void agg_mfma(
    const int* __restrict__ history, const int* __restrict__ degrees,
    const float* __restrict__ v_to_e,
    const float* __restrict__ att2_w, const float* __restrict__ att2_b,
    const float* __restrict__ att3_w,
    const float* __restrict__ P, const float* __restrict__ S,
    float* __restrict__ out, int Bn, int K)
{
    __shared__ float att_lds[4][64];
    const int wslot = threadIdx.x >> 6;
    const int b = (int)blockIdx.x * 4 + wslot;
    if (b >= Bn) return;
    const int l  = threadIdx.x & 63;
    const int lg = l >> 4;        // k-slice group 0..3
    const int lc = l & 15;        // row (A) / col (B,D) within 16-tile
    const int deg = degrees[b];   // wave-uniform

    // ---- B operand: W2 fragments, B[d][e] = W2[e][d]; held whole kernel ----
    bf16x8 w2f[4][2];
#pragma unroll
    for (int tc = 0; tc < 4; ++tc)
#pragma unroll
        for (int ks = 0; ks < 2; ++ks) {
            const float* src = att2_w + (tc * 16 + lc) * D + ks * 32 + lg * 8;
            const float4 a = *(const float4*)src;
            const float4 c = *(const float4*)(src + 4);
            bf16x8 f;
            f[0] = f2bf(a.x); f[1] = f2bf(a.y); f[2] = f2bf(a.z); f[3] = f2bf(a.w);
            f[4] = f2bf(c.x); f[5] = f2bf(c.y); f[6] = f2bf(c.z); f[7] = f2bf(c.w);
            w2f[tc][ks] = f;
        }
    float b2f[4], w3f[4];
#pragma unroll
    for (int tc = 0; tc < 4; ++tc) {
        b2f[tc] = att2_b[tc * 16 + lc];
        w3f[tc] = att3_w[tc * 16 + lc];
    }

    // ---- neighbor row ids for A-frag rows: row k' = tr*16 + lc ----
    int vrow[4];
#pragma unroll
    for (int tr = 0; tr < 4; ++tr) {
        int kk = tr * 16 + lc;
        if (kk > K - 1) kk = K - 1;                 // pad rows; masked later
        vrow[tr] = history[(size_t)b * K + kk];
    }

    // ---- MFMA accumulation: acc[tr][tc] += A(tr,ks) * B(tc,ks) ----
    f32x4 acc[4][4];
#pragma unroll
    for (int i = 0; i < 4; ++i)
#pragma unroll
        for (int j = 0; j < 4; ++j) acc[i][j] = (f32x4)0.f;

#pragma unroll
    for (int ks = 0; ks < 2; ++ks) {
        const float* sp = S + (size_t)b * D + ks * 32 + lg * 8;  // uniform/16-grp
        const float4 s0 = *(const float4*)sp;
        const float4 s1 = *(const float4*)(sp + 4);
#pragma unroll
        for (int tr = 0; tr < 4; ++tr) {
            const float* pp = P + (size_t)vrow[tr] * D + ks * 32 + lg * 8;
            const float4 p0 = *(const float4*)pp;
            const float4 p1 = *(const float4*)(pp + 4);
            bf16x8 af;
            af[0] = f2bf(fmaxf(p0.x + s0.x, 0.f));
            af[1] = f2bf(fmaxf(p0.y + s0.y, 0.f));
            af[2] = f2bf(fmaxf(p0.z + s0.z, 0.f));
            af[3] = f2bf(fmaxf(p0.w + s0.w, 0.f));
            af[4] = f2bf(fmaxf(p1.x + s1.x, 0.f));
            af[5] = f2bf(fmaxf(p1.y + s1.y, 0.f));
            af[6] = f2bf(fmaxf(p1.z + s1.z, 0.f));
            af[7] = f2bf(fmaxf(p1.w + s1.w, 0.f));
#pragma unroll
            for (int tc = 0; tc < 4; ++tc)
                acc[tr][tc] = __builtin_amdgcn_mfma_f32_16x16x32_bf16(
                    af, w2f[tc][ks], acc[tr][tc], 0, 0, 0);
        }
    }

    // ---- epilogue: logit[k] = sum_e relu(H2[k,e] + b2[e]) * w3[e] ----
    float part[4][4];                                // [tr][r], k = tr*16+lg*4+r
#pragma unroll
    for (int tr = 0; tr < 4; ++tr)
#pragma unroll
        for (int r = 0; r < 4; ++r) {
            float v = 0.f;
#pragma unroll
            for (int tc = 0; tc < 4; ++tc) {
                const float h2 = fmaxf(acc[tr][tc][r] + b2f[tc], 0.f);
                v += h2 * w3f[tc];
            }
            part[tr][r] = v;
        }
    // reduce across the 16 col-lanes (lc) of each group
#pragma unroll
    for (int off = 1; off < 16; off <<= 1)
#pragma unroll
        for (int tr = 0; tr < 4; ++tr)
#pragma unroll
            for (int r = 0; r < 4; ++r)
                part[tr][r] += __shfl_xor(part[tr][r], off);

    // ---- masked softmax over k = tr*16 + lg*4 + r ----
#pragma unroll
    for (int tr = 0; tr < 4; ++tr)
#pragma unroll
        for (int r = 0; r < 4; ++r) {
            const int k = tr * 16 + lg * 4 + r;
            if (k >= deg) part[tr][r] = -1e30f;
        }
    float m = -1e30f;
#pragma unroll
    for (int tr = 0; tr < 4; ++tr)
#pragma unroll
        for (int r = 0; r < 4; ++r) m = fmaxf(m, part[tr][r]);
    m = fmaxf(m, __shfl_xor(m, 16));
    m = fmaxf(m, __shfl_xor(m, 32));

    float sum = 0.f;
#pragma unroll
    for (int tr = 0; tr < 4; ++tr)
#pragma unroll
        for (int r = 0; r < 4; ++r) {
            part[tr][r] = __expf(part[tr][r] - m);   // masked -> exp(-1e30) = 0
            sum += part[tr][r];
        }
    sum += __shfl_xor(sum, 16);
    sum += __shfl_xor(sum, 32);
    const float inv = 1.f / sum;

    if (lc == 0) {
#pragma unroll
        for (int tr = 0; tr < 4; ++tr)
#pragma unroll
            for (int r = 0; r < 4; ++r)
                att_lds[wslot][tr * 16 + lg * 4 + r] = part[tr][r] * inv;
    }
    // same-wave LDS write->read: in-order DS pipe, no barrier needed

    // ---- value path (fp32): out[b, l] = sum_k att[k] * v_to_e[v_k, l] ----
    float od = 0.f;
    for (int k = 0; k < deg; ++k) {
        const float a  = att_lds[wslot][k];
        const int   vk = history[(size_t)b * K + k];   // uniform -> s_load
        od += a * v_to_e[(size_t)vk * D + l];
    }
    out[(size_t)b * D + l] = od;
}

// ---------------------------------------------------------------------------
// Fallback (no workspace): R1's fused fp32 kernel, one wave per b.
// ---------------------------------------------------------------------------
__global__ __launch_bounds__(256) void agg_fallback(
    const int* __restrict__ nodes, const int* __restrict__ history,
    const int* __restrict__ degrees,
    const float* __restrict__ u_to_e, const float* __restrict__ v_to_e,
    const float* __restrict__ att1_w, const float* __restrict__ att1_b,
    const float* __restrict__ att2_w, const float* __restrict__ att2_b,
    const float* __restrict__ att3_w, const float* __restrict__ att3_b,
    float* __restrict__ out, int Bn, int K)
{
    const int b    = (int)((blockIdx.x * blockDim.x + threadIdx.x) >> 6);
    const int lane = threadIdx.x & 63;
    if (b >= Bn) return;

    const int  deg    = degrees[b];
    const bool active = (lane < deg);
    const int  v      = history[(size_t)b * K + ((lane < K) ? lane : 0)];

    float h1[D];
    float vr[D];
    const float4* v4 = (const float4*)(v_to_e + (size_t)v * D);
#pragma unroll
    for (int i = 0; i < D / 4; ++i) {
        float4 t = v4[i];
        vr[4 * i + 0] = t.x; vr[4 * i + 1] = t.y;
        vr[4 * i + 2] = t.z; vr[4 * i + 3] = t.w;
    }
    const float* urow = u_to_e + (size_t)nodes[b] * D;
#pragma unroll
    for (int d = 0; d < D; ++d) {
        const float* w1 = att1_w + d * TWO_D;
        float a0 = att1_b[d], a1 = 0.f, a2 = 0.f, a3 = 0.f;
#pragma unroll
        for (int f = 0; f < D; f += 4) {
            a0 += vr[f + 0] * w1[f + 0];
            a1 += vr[f + 1] * w1[f + 1];
            a2 += vr[f + 2] * w1[f + 2];
            a3 += vr[f + 3] * w1[f + 3];
            a0 += urow[f + 0] * w1[D + f + 0];
            a1 += urow[f + 1] * w1[D + f + 1];
            a2 += urow[f + 2] * w1[D + f + 2];
            a3 += urow[f + 3] * w1[D + f + 3];
        }
        h1[d] = fmaxf((a0 + a1) + (a2 + a3), 0.f);
    }

    float logit = att3_b[0];
#pragma unroll 4
    for (int e = 0; e < D; ++e) {
        const float* w2r = att2_w + e * D;
        float a0 = 0.f, a1 = 0.f, a2 = 0.f, a3 = 0.f;
#pragma unroll
        for (int dd = 0; dd < D; dd += 4) {
            a0 += h1[dd + 0] * w2r[dd + 0];
            a1 += h1[dd + 1] * w2r[dd + 1];
            a2 += h1[dd + 2] * w2r[dd + 2];
            a3 += h1[dd + 3] * w2r[dd + 3];
        }
        float h2 = (a0 + a1) + (a2 + a3) + att2_b[e];
        logit += fmaxf(h2, 0.f) * att3_w[e];
    }

    float ml = active ? logit : -1e30f;
#pragma unroll
    for (int off = 32; off > 0; off >>= 1) ml = fmaxf(ml, __shfl_xor(ml, off));
    const float ex = active ? __expf(logit - ml) : 0.f;
    float sm = ex;
#pragma unroll
    for (int off = 32; off > 0; off >>= 1) sm += __shfl_xor(sm, off);
    const float att = ex / sm;

    float acc = 0.f;
    for (int kk = 0; kk < deg; ++kk) {
        const float a  = __shfl(att, kk);
        const int   vk = __shfl(v, kk);
        acc += a * v_to_e[(size_t)vk * D + lane];
    }
    out[(size_t)b * D + lane] = acc;
}

// ---------------------------------------------------------------------------
extern "C" void kernel_launch(void* const* d_in, const int* in_sizes, int n_in,
                              void* d_out, int out_size, void* d_ws, size_t ws_size,
                              hipStream_t stream)
{
    const int*   nodes   = (const int*)d_in[0];
    const int*   history = (const int*)d_in[1];
    const int*   degrees = (const int*)d_in[2];
    const float* u_to_e  = (const float*)d_in[3];
    const float* v_to_e  = (const float*)d_in[4];
    const float* att1_w  = (const float*)d_in[5];
    const float* att1_b  = (const float*)d_in[6];
    const float* att2_w  = (const float*)d_in[7];
    const float* att2_b  = (const float*)d_in[8];
    const float* att3_w  = (const float*)d_in[9];
    const float* att3_b  = (const float*)d_in[10];
    float*       out     = (float*)d_out;

    const int Bn = in_sizes[0];
    const int K  = in_sizes[1] / Bn;
    const int NV = in_sizes[4] / D;

    const size_t need = ((size_t)NV + (size_t)Bn) * D * sizeof(float);

    if (ws_size >= need) {
        float* P = (float*)d_ws;
        float* S = P + (size_t)NV * D;
        const int nPB = (NV + 63) / 64;
        const int nSB = (Bn + 63) / 64;
        proj_gemm<<<nPB + nSB, 256, 0, stream>>>(
            v_to_e, u_to_e, nodes, att1_w, att1_b, P, S, NV, Bn, nPB);
        agg_mfma<<<(Bn + 3) / 4, 256, 0, stream>>>(
            history, degrees, v_to_e, att2_w, att2_b, att3_w,
            P, S, out, Bn, K);
    } else {
        const int agg_blocks = (Bn * 64 + 255) / 256;
        agg_fallback<<<agg_blocks, 256, 0, stream>>>(
            nodes, history, degrees, u_to_e, v_to_e,
            att1_w, att1_b, att2_w, att2_b, att3_w, att3_b,
            out, Bn, K);
    }
}

// Round 5
// 66.540 us; speedup vs baseline: 9.2726x; 1.2535x over previous
//
#include <hip/hip_runtime.h>
#include <cstdint>
#include <cstddef>

constexpr int D = 64;
constexpr int TWO_D = 128;

typedef __attribute__((ext_vector_type(8))) short bf16x8;
typedef __attribute__((ext_vector_type(4))) float f32x4;
typedef __attribute__((ext_vector_type(4))) unsigned short u16x4;

static __device__ __forceinline__ short f2bf(float x) {
    unsigned u = __builtin_bit_cast(unsigned, x);
    u += 0x7fffu + ((u >> 16) & 1u);          // round-to-nearest-even
    return (short)(u >> 16);
}
static __device__ __forceinline__ float bf2f(short h) {
    return __builtin_bit_cast(float, ((unsigned)(unsigned short)h) << 16);
}
static __device__ __forceinline__ float readlane_f(float v, int lane) {
    return __builtin_bit_cast(float,
        __builtin_amdgcn_readlane(__builtin_bit_cast(int, v), lane));
}

// ---------------------------------------------------------------------------
// Kernel 1: projection tables, tiled fp32 GEMM (R3 structure).
//   blocks [0, nPB):        P16[r,:] = bf16( v_to_e[r,:] . att1_w[:,0:D]^T )
//   blocks [nPB, nPB+nSB):  S[b,:]   = u_to_e[nodes[b],:] . att1_w[:,D:2D]^T + b1
// P is written in bf16 (128 B rows) so agg's A-fragment gathers are 16B/lane
// loads that consume whole 64B granules.
// ---------------------------------------------------------------------------
__global__ __launch_bounds__(256) void proj_gemm(
    const float* __restrict__ v_to_e, const float* __restrict__ u_to_e,
    const int* __restrict__ nodes,
    const float* __restrict__ att1_w, const float* __restrict__ att1_b,
    unsigned short* __restrict__ P16, float* __restrict__ S,
    int NV, int Bn, int nPB)
{
    constexpr int ST = 68;
    __shared__ float xs[64 * ST];
    __shared__ float ws[64 * ST];

    const int tid  = threadIdx.x;
    const bool isS = ((int)blockIdx.x >= nPB);
    const int base = (isS ? ((int)blockIdx.x - nPB) : (int)blockIdx.x) * 64;
    const int nRows = isS ? Bn : NV;
    const int woff  = isS ? D : 0;
    const float* X  = isS ? u_to_e : v_to_e;

#pragma unroll
    for (int it = 0; it < 4; ++it) {
        const int flat = it * 256 + tid;
        const int dd = flat >> 4, f4 = flat & 15;
        const float4 w = *(const float4*)(att1_w + dd * TWO_D + woff + f4 * 4);
        ws[(f4 * 4 + 0) * ST + dd] = w.x;
        ws[(f4 * 4 + 1) * ST + dd] = w.y;
        ws[(f4 * 4 + 2) * ST + dd] = w.z;
        ws[(f4 * 4 + 3) * ST + dd] = w.w;
    }
#pragma unroll
    for (int it = 0; it < 4; ++it) {
        const int flat = it * 256 + tid;
        const int r = flat >> 4, f4 = flat & 15;
        int gr = base + r;
        if (gr >= nRows) gr = nRows - 1;
        const int row = isS ? nodes[gr] : gr;
        const float4 x = *(const float4*)(X + (size_t)row * D + f4 * 4);
        xs[(f4 * 4 + 0) * ST + r] = x.x;
        xs[(f4 * 4 + 1) * ST + r] = x.y;
        xs[(f4 * 4 + 2) * ST + r] = x.z;
        xs[(f4 * 4 + 3) * ST + r] = x.w;
    }
    __syncthreads();

    const int d0 = (tid & 15) * 4;
    const int r0 = (tid >> 4) * 4;
    float acc[4][4];
#pragma unroll
    for (int i = 0; i < 4; ++i)
#pragma unroll
        for (int j = 0; j < 4; ++j) acc[i][j] = 0.f;

#pragma unroll 8
    for (int f = 0; f < D; ++f) {
        const float4 w = *(const float4*)&ws[f * ST + d0];
        const float4 x = *(const float4*)&xs[f * ST + r0];
        const float wv[4] = {w.x, w.y, w.z, w.w};
        const float xv[4] = {x.x, x.y, x.z, x.w};
#pragma unroll
        for (int ri = 0; ri < 4; ++ri)
#pragma unroll
            for (int di = 0; di < 4; ++di)
                acc[ri][di] += xv[ri] * wv[di];
    }

    if (isS) {
        float bv[4];
#pragma unroll
        for (int di = 0; di < 4; ++di) bv[di] = att1_b[d0 + di];
#pragma unroll
        for (int ri = 0; ri < 4; ++ri) {
            const int gr = base + r0 + ri;
            if (gr < nRows) {
                float4 o = {acc[ri][0] + bv[0], acc[ri][1] + bv[1],
                            acc[ri][2] + bv[2], acc[ri][3] + bv[3]};
                *(float4*)(S + (size_t)gr * D + d0) = o;
            }
        }
    } else {
#pragma unroll
        for (int ri = 0; ri < 4; ++ri) {
            const int gr = base + r0 + ri;
            if (gr < nRows) {
                u16x4 o;
                o[0] = (unsigned short)f2bf(acc[ri][0]);
                o[1] = (unsigned short)f2bf(acc[ri][1]);
                o[2] = (unsigned short)f2bf(acc[ri][2]);
                o[3] = (unsigned short)f2bf(acc[ri][3]);
                *(u16x4*)(P16 + (size_t)gr * D + d0) = o;
            }
        }
    }
}

// ---------------------------------------------------------------------------
// Kernel 2 (MFMA): one wave per node b (4 waves / block). Score path:
// H2 = relu(P16[v]+S[b]) @ W2^T via 32x mfma_f32_16x16x32_bf16, epilogue
// relu+b2, dot w3, shfl-reduce -> logits, masked softmax IN REGISTERS.
// Value path: att and row ids broadcast via v_readlane (SGPR), coalesced
// v_to_e row loads, 4 independent accumulator chains. No LDS at all.
// ---------------------------------------------------------------------------
__global__ __launch_bounds__(256) void agg_mfma(
    const int* __restrict__ history, const int* __restrict__ degrees,
    const float* __restrict__ v_to_e,
    const float* __restrict__ att2_w, const float* __restrict__ att2_b,
    const float* __restrict__ att3_w,
    const unsigned short* __restrict__ P16, const float* __restrict__ S,
    float* __restrict__ out, int Bn, int K)
{
    const int b = (int)blockIdx.x * 4 + (threadIdx.x >> 6);
    if (b >= Bn) return;
    const int l  = threadIdx.x & 63;
    const int lg = l >> 4;        // k-slice group 0..3
    const int lc = l & 15;        // row (A) / col (B,D) within 16-tile
    const int deg = degrees[b];   // wave-uniform

    // ---- B operand: W2 fragments, B[d][e] = W2[e][d]; held whole kernel ----
    bf16x8 w2f[4][2];
#pragma unroll
    for (int tc = 0; tc < 4; ++tc)
#pragma unroll
        for (int ks = 0; ks < 2; ++ks) {
            const float* src = att2_w + (tc * 16 + lc) * D + ks * 32 + lg * 8;
            const float4 a = *(const float4*)src;
            const float4 c = *(const float4*)(src + 4);
            bf16x8 f;
            f[0] = f2bf(a.x); f[1] = f2bf(a.y); f[2] = f2bf(a.z); f[3] = f2bf(a.w);
            f[4] = f2bf(c.x); f[5] = f2bf(c.y); f[6] = f2bf(c.z); f[7] = f2bf(c.w);
            w2f[tc][ks] = f;
        }
    float b2f[4], w3f[4];
#pragma unroll
    for (int tc = 0; tc < 4; ++tc) {
        b2f[tc] = att2_b[tc * 16 + lc];
        w3f[tc] = att3_w[tc * 16 + lc];
    }

    // ---- neighbor row ids for A-frag rows: row k' = tr*16 + lc ----
    int vrow[4];
#pragma unroll
    for (int tr = 0; tr < 4; ++tr) {
        int kk = tr * 16 + lc;
        if (kk > K - 1) kk = K - 1;                 // pad rows; att=0 later
        vrow[tr] = history[(size_t)b * K + kk];
    }

    // ---- MFMA accumulation ----
    f32x4 acc[4][4];
#pragma unroll
    for (int i = 0; i < 4; ++i)
#pragma unroll
        for (int j = 0; j < 4; ++j) acc[i][j] = (f32x4)0.f;

#pragma unroll
    for (int ks = 0; ks < 2; ++ks) {
        const float* sp = S + (size_t)b * D + ks * 32 + lg * 8;
        const float4 s0 = *(const float4*)sp;
        const float4 s1 = *(const float4*)(sp + 4);
        const float sv[8] = {s0.x, s0.y, s0.z, s0.w, s1.x, s1.y, s1.z, s1.w};
#pragma unroll
        for (int tr = 0; tr < 4; ++tr) {
            // one 16B load: 64 lanes consume 16 whole 64B granules
            const bf16x8 praw = *(const bf16x8*)(
                P16 + (size_t)vrow[tr] * D + ks * 32 + lg * 8);
            bf16x8 af;
#pragma unroll
            for (int j = 0; j < 8; ++j)
                af[j] = f2bf(fmaxf(bf2f(praw[j]) + sv[j], 0.f));
#pragma unroll
            for (int tc = 0; tc < 4; ++tc)
                acc[tr][tc] = __builtin_amdgcn_mfma_f32_16x16x32_bf16(
                    af, w2f[tc][ks], acc[tr][tc], 0, 0, 0);
        }
    }

    // ---- epilogue: logit[k] = sum_e relu(H2[k,e]+b2[e]) * w3[e] ----
    float part[4][4];                    // [tr][r], k = tr*16 + lg*4 + r
#pragma unroll
    for (int tr = 0; tr < 4; ++tr)
#pragma unroll
        for (int r = 0; r < 4; ++r) {
            float v = 0.f;
#pragma unroll
            for (int tc = 0; tc < 4; ++tc) {
                const float h2 = fmaxf(acc[tr][tc][r] + b2f[tc], 0.f);
                v += h2 * w3f[tc];
            }
            part[tr][r] = v;
        }
#pragma unroll
    for (int off = 1; off < 16; off <<= 1)
#pragma unroll
        for (int tr = 0; tr < 4; ++tr)
#pragma unroll
            for (int r = 0; r < 4; ++r)
                part[tr][r] += __shfl_xor(part[tr][r], off);

    // ---- masked softmax (in registers) ----
#pragma unroll
    for (int tr = 0; tr < 4; ++tr)
#pragma unroll
        for (int r = 0; r < 4; ++r) {
            const int k = tr * 16 + lg * 4 + r;
            if (k >= deg) part[tr][r] = -1e30f;
        }
    float m = -1e30f;
#pragma unroll
    for (int tr = 0; tr < 4; ++tr)
#pragma unroll
        for (int r = 0; r < 4; ++r) m = fmaxf(m, part[tr][r]);
    m = fmaxf(m, __shfl_xor(m, 16));
    m = fmaxf(m, __shfl_xor(m, 32));

    float sum = 0.f;
#pragma unroll
    for (int tr = 0; tr < 4; ++tr)
#pragma unroll
        for (int r = 0; r < 4; ++r) {
            part[tr][r] = __expf(part[tr][r] - m);   // 0 for masked k
            sum += part[tr][r];
        }
    sum += __shfl_xor(sum, 16);
    sum += __shfl_xor(sum, 32);
    const float inv = 1.f / sum;
#pragma unroll
    for (int tr = 0; tr < 4; ++tr)
#pragma unroll
        for (int r = 0; r < 4; ++r) part[tr][r] *= inv;
    // part[tr][r] now = att[k], identical across the 16 lc-lanes of group lg.

    // ---- value path: out[b,l] = sum_k att[k] * v_to_e[v_k, l] ----
    // att[k] lives in lane ((k>>2)&3)*16 reg part[k>>4][k&3];
    // v_k lives in lane (k&15) reg vrow[k>>4].  All readlane indices static.
    float od[4] = {0.f, 0.f, 0.f, 0.f};
#pragma unroll
    for (int tr = 0; tr < 4; ++tr) {
        if (tr * 16 < deg) {              // wave-uniform chunk skip
#pragma unroll
            for (int j = 0; j < 16; ++j) {
                const float a  = readlane_f(part[tr][j & 3], (j >> 2) << 4);
                const int   vk = __builtin_amdgcn_readlane(vrow[tr], j);
                od[tr] += a * v_to_e[(size_t)vk * D + l];
            }
        }
    }
    out[(size_t)b * D + l] = (od[0] + od[1]) + (od[2] + od[3]);
}

// ---------------------------------------------------------------------------
// Fallback (no workspace): fused fp32 kernel, one wave per b.
// ---------------------------------------------------------------------------
__global__ __launch_bounds__(256) void agg_fallback(
    const int* __restrict__ nodes, const int* __restrict__ history,
    const int* __restrict__ degrees,
    const float* __restrict__ u_to_e, const float* __restrict__ v_to_e,
    const float* __restrict__ att1_w, const float* __restrict__ att1_b,
    const float* __restrict__ att2_w, const float* __restrict__ att2_b,
    const float* __restrict__ att3_w, const float* __restrict__ att3_b,
    float* __restrict__ out, int Bn, int K)
{
    const int b    = (int)((blockIdx.x * blockDim.x + threadIdx.x) >> 6);
    const int lane = threadIdx.x & 63;
    if (b >= Bn) return;

    const int  deg    = degrees[b];
    const bool active = (lane < deg);
    const int  v      = history[(size_t)b * K + ((lane < K) ? lane : 0)];

    float h1[D];
    float vr[D];
    const float4* v4 = (const float4*)(v_to_e + (size_t)v * D);
#pragma unroll
    for (int i = 0; i < D / 4; ++i) {
        float4 t = v4[i];
        vr[4 * i + 0] = t.x; vr[4 * i + 1] = t.y;
        vr[4 * i + 2] = t.z; vr[4 * i + 3] = t.w;
    }
    const float* urow = u_to_e + (size_t)nodes[b] * D;
#pragma unroll
    for (int d = 0; d < D; ++d) {
        const float* w1 = att1_w + d * TWO_D;
        float a0 = att1_b[d], a1 = 0.f, a2 = 0.f, a3 = 0.f;
#pragma unroll
        for (int f = 0; f < D; f += 4) {
            a0 += vr[f + 0] * w1[f + 0];
            a1 += vr[f + 1] * w1[f + 1];
            a2 += vr[f + 2] * w1[f + 2];
            a3 += vr[f + 3] * w1[f + 3];
            a0 += urow[f + 0] * w1[D + f + 0];
            a1 += urow[f + 1] * w1[D + f + 1];
            a2 += urow[f + 2] * w1[D + f + 2];
            a3 += urow[f + 3] * w1[D + f + 3];
        }
        h1[d] = fmaxf((a0 + a1) + (a2 + a3), 0.f);
    }

    float logit = att3_b[0];
#pragma unroll 4
    for (int e = 0; e < D; ++e) {
        const float* w2r = att2_w + e * D;
        float a0 = 0.f, a1 = 0.f, a2 = 0.f, a3 = 0.f;
#pragma unroll
        for (int dd = 0; dd < D; dd += 4) {
            a0 += h1[dd + 0] * w2r[dd + 0];
            a1 += h1[dd + 1] * w2r[dd + 1];
            a2 += h1[dd + 2] * w2r[dd + 2];
            a3 += h1[dd + 3] * w2r[dd + 3];
        }
        float h2 = (a0 + a1) + (a2 + a3) + att2_b[e];
        logit += fmaxf(h2, 0.f) * att3_w[e];
    }

    float ml = active ? logit : -1e30f;
#pragma unroll
    for (int off = 32; off > 0; off >>= 1) ml = fmaxf(ml, __shfl_xor(ml, off));
    const float ex = active ? __expf(logit - ml) : 0.f;
    float sm = ex;
#pragma unroll
    for (int off = 32; off > 0; off >>= 1) sm += __shfl_xor(sm, off);
    const float att = ex / sm;

    float acc = 0.f;
    for (int kk = 0; kk < deg; ++kk) {
        const float a  = __shfl(att, kk);
        const int   vk = __shfl(v, kk);
        acc += a * v_to_e[(size_t)vk * D + lane];
    }
    out[(size_t)b * D + lane] = acc;
}

// ---------------------------------------------------------------------------
extern "C" void kernel_launch(void* const* d_in, const int* in_sizes, int n_in,
                              void* d_out, int out_size, void* d_ws, size_t ws_size,
                              hipStream_t stream)
{
    const int*   nodes   = (const int*)d_in[0];
    const int*   history = (const int*)d_in[1];
    const int*   degrees = (const int*)d_in[2];
    const float* u_to_e  = (const float*)d_in[3];
    const float* v_to_e  = (const float*)d_in[4];
    const float* att1_w  = (const float*)d_in[5];
    const float* att1_b  = (const float*)d_in[6];
    const float* att2_w  = (const float*)d_in[7];
    const float* att2_b  = (const float*)d_in[8];
    const float* att3_w  = (const float*)d_in[9];
    const float* att3_b  = (const float*)d_in[10];
    float*       out     = (float*)d_out;

    const int Bn = in_sizes[0];
    const int K  = in_sizes[1] / Bn;
    const int NV = in_sizes[4] / D;

    // workspace: P16 (bf16, NV*D) then S (fp32, Bn*D), both naturally aligned
    const size_t p16_bytes = (size_t)NV * D * sizeof(unsigned short);
    const size_t need = p16_bytes + (size_t)Bn * D * sizeof(float);

    if (ws_size >= need) {
        unsigned short* P16 = (unsigned short*)d_ws;
        float* S = (float*)((char*)d_ws + p16_bytes);
        const int nPB = (NV + 63) / 64;
        const int nSB = (Bn + 63) / 64;
        proj_gemm<<<nPB + nSB, 256, 0, stream>>>(
            v_to_e, u_to_e, nodes, att1_w, att1_b, P16, S, NV, Bn, nPB);
        agg_mfma<<<(Bn + 3) / 4, 256, 0, stream>>>(
            history, degrees, v_to_e, att2_w, att2_b, att3_w,
            P16, S, out, Bn, K);
    } else {
        const int agg_blocks = (Bn * 64 + 255) / 256;
        agg_fallback<<<agg_blocks, 256, 0, stream>>>(
            nodes, history, degrees, u_to_e, v_to_e,
            att1_w, att1_b, att2_w, att2_b, att3_w, att3_b,
            out, Bn, K);
    }
}